// Round 8
// baseline (461.455 us; speedup 1.0000x reference)
//
#include <hip/hip_runtime.h>
#include <hip/hip_bf16.h>
#include <math.h>

// ---------------------------------------------------------------------------
// VQ quantizer:
//   in[0] = z        (16,256,32,32) fp32   -> N=16384 vectors of C=256
//   in[1] = codebook (8192,256)     fp32
//   out   = [ z_q (B,C,H,W) 4194304 | loss | ortho | perplexity | idx(16384) as float ]
//
// idx strategy (two-stage, bit-matching the R2..R7 passing semantics):
//   Stage A: bf16 MFMA GEMM; tilemin[t][n] = -2*max_j dot_approx (err<=1.54e-4)
//            (same MFMA shape + same kc/kk accumulation order as R7 -> bits ==)
//   Stage B: rows whose tilemin is within MARGIN of rowmin get the EXACT fp32
//            chain recomputed tile-centrically; d = fmaf(-2,acc, A_n + ce_j)
//            == R2 bits; packed-key atomicMin, lowest-index tie-break.
// ---------------------------------------------------------------------------

#define N_E     8192
#define C_DIM   256
#define N_VEC   16384            // 16*32*32
#define N_ELEM  4194304          // 16*256*32*32
#define MARGIN  6.0e-4f

// ws layout (bytes) -- zero-init fields packed first (single memset)
#define WS_COUNTS   0            // int[8192]                 32768
#define WS_M        32768        // float[65536]              262144
#define WS_ACCUM    294912       // double[2]                 16
#define WS_LISTLEN  294928       // int[64]                   256
#define WS_ZERO_BYTES 295184
#define WS_CE       295184       // float[8192]               32768
#define WS_RN       327952       // float[8192]               32768
#define WS_A        360720       // float[16384]              65536
#define WS_KEYS     426256       // u64[16384]                131072
#define WS_LISTS    557328       // int[64*16384]             4194304
#define WS_TILEMIN  4751632      // float[64*16384] [t][n]    4194304
#define WS_ZBF      8945936      // ushort[16384*256]         8388608
#define WS_CBBF     17334544     // ushort[8192*256]          4194304
#define WS_THR      21528848     // float[16384]              65536

typedef short short8v __attribute__((ext_vector_type(8)));
typedef float f32x4  __attribute__((ext_vector_type(4)));

__device__ inline unsigned short f2bf(float f) {       // RNE fp32->bf16 (no NaN in data)
    unsigned int x = __float_as_uint(f);
    return (unsigned short)((x + 0x7fffu + ((x >> 16) & 1u)) >> 16);
}

// ---------------------------------------------------------------------------
// codebook prep: row sqnorm ce (bits == R2..R7), recip norm rn, bf16 cast
__global__ __launch_bounds__(256) void k_cbprep(const float* __restrict__ cb,
                                                float* __restrict__ ce,
                                                float* __restrict__ rn,
                                                unsigned short* __restrict__ cbbf) {
    int j = blockIdx.x;
    int tid = threadIdx.x;
    float v = cb[(size_t)j * C_DIM + tid];
    cbbf[(size_t)j * C_DIM + tid] = f2bf(v);
    float s = v * v;
    #pragma unroll
    for (int off = 32; off > 0; off >>= 1) s += __shfl_down(s, off, 64);
    __shared__ float sh[4];
    if ((tid & 63) == 0) sh[tid >> 6] = s;
    __syncthreads();
    if (tid == 0) {
        float t = sh[0] + sh[1] + sh[2] + sh[3];
        ce[j] = t;
        rn[j] = 1.0f / sqrtf(t);
    }
}

// ---------------------------------------------------------------------------
// z prep: bf16 transpose chunk write; blockIdx.y==0 additionally computes the
// canonical A[n] chain (verbatim R2 body -> identical bits).
__global__ __launch_bounds__(256) void k_ztrans(const float* __restrict__ z,
                                                unsigned short* __restrict__ zbf,
                                                float* __restrict__ A) {
    int n = blockIdx.x * 256 + threadIdx.x;
    int b = n >> 10, hw = n & 1023;
    int c0 = blockIdx.y * 64;
    const float* zp = z + (size_t)b * 262144 + hw;
    #pragma unroll 8
    for (int c = c0; c < c0 + 64; ++c)
        zbf[(size_t)n * C_DIM + c] = f2bf(zp[(size_t)c * 1024]);
    if (blockIdx.y == 0) {
        float a = 0.0f;
        #pragma unroll 8
        for (int c = 0; c < C_DIM; ++c) {
            float v = zp[(size_t)c * 1024];
            a = fmaf(v, v, a);
        }
        A[n] = a;
    }
}

// ---------------------------------------------------------------------------
// Stage A: bf16 MFMA GEMM, 256n x 256j per block, 8 waves (2M x 4N), wave tile
// 128n x 64j, BK=64 double-buffered (dynamic LDS 144 KB, padded 72-short rows
// -> all ds ops <=2-way).  Reg-staged pipeline with RAW s_barrier (no vmcnt(0)
// drain): next K-chunk's global loads issue before the MFMAs and their latency
// hides under compute.  kc/kk accumulation order identical to R7 -> tilemin
// bits unchanged.  Epilogue: tilemin[bx*2+h][n] = -2*max_j dot over 128-j tile.
#define AMF_LDSB 36864        // shorts per buffer: (256 + 256) * 72

__global__ __launch_bounds__(512, 2) void k_mfma(const unsigned short* __restrict__ zbf,
                                                 const unsigned short* __restrict__ cbbf,
                                                 float* __restrict__ tilemin) {
    extern __shared__ unsigned short lds[];     // [2][512][72]
    __shared__ float smin[2][256][2];           // [j-half][row][wn&1]

    const int tid = threadIdx.x;                // 0..511
    const int w = tid >> 6, l = tid & 63;
    const int wm = w >> 2, wn = w & 3;          // 2M x 4N wave grid
    const int g = l >> 4, c = l & 15;

    // XCD-chunked block swizzle: XCD x owns by in [8x, 8x+8), sweeps bx inner
    const int lin = blockIdx.x;                 // 0..2047
    const int x = lin & 7, rnk = lin >> 3;
    const int by = x * 8 + (rnk >> 5), bx = rnk & 31;
    const int n0 = by * 256, j0 = bx * 256;

    // staging: thread covers rows (tid>>3) + 64i, 16B slot tid&7 (4 insts each)
    const int srow = tid >> 3, sslot = tid & 7;
    const unsigned short* gA = zbf  + (size_t)(n0 + srow) * C_DIM + sslot * 8;
    const unsigned short* gB = cbbf + (size_t)(j0 + srow) * C_DIM + sslot * 8;

    short8v ra[4], rb[4];
    #pragma unroll
    for (int i = 0; i < 4; ++i) {               // K-chunk 0
        ra[i] = *(const short8v*)(gA + (size_t)i * 64 * C_DIM);
        rb[i] = *(const short8v*)(gB + (size_t)i * 64 * C_DIM);
    }

    f32x4 acc[8][4];
    #pragma unroll
    for (int nf = 0; nf < 8; ++nf)
        #pragma unroll
        for (int jf = 0; jf < 4; ++jf) acc[nf][jf] = (f32x4){0.f, 0.f, 0.f, 0.f};

    #pragma unroll
    for (int t = 0; t < 4; ++t) {
        const int s = t & 1;
        unsigned short* Ab = lds + s * AMF_LDSB;
        unsigned short* Bb = Ab + 256 * 72;
        #pragma unroll
        for (int i = 0; i < 4; ++i) {           // LDS store of chunk t
            *(short8v*)&Ab[(srow + 64 * i) * 72 + sslot * 8] = ra[i];
            *(short8v*)&Bb[(srow + 64 * i) * 72 + sslot * 8] = rb[i];
        }
        if (t < 3) {                            // early-issue next chunk (T14)
            #pragma unroll
            for (int i = 0; i < 4; ++i) {
                ra[i] = *(const short8v*)(gA + (size_t)i * 64 * C_DIM + (t + 1) * 64);
                rb[i] = *(const short8v*)(gB + (size_t)i * 64 * C_DIM + (t + 1) * 64);
            }
        }
        asm volatile("s_waitcnt lgkmcnt(0)" ::: "memory");   // own ds_writes done
        __builtin_amdgcn_sched_barrier(0);
        __builtin_amdgcn_s_barrier();                        // buffer s ready
        __builtin_amdgcn_sched_barrier(0);

        __builtin_amdgcn_s_setprio(1);
        #pragma unroll
        for (int kk = 0; kk < 2; ++kk) {
            short8v a[8], b[4];
            #pragma unroll
            for (int nf = 0; nf < 8; ++nf)
                a[nf] = *(const short8v*)&Ab[(wm * 128 + nf * 16 + c) * 72 + kk * 32 + g * 8];
            #pragma unroll
            for (int jf = 0; jf < 4; ++jf)
                b[jf] = *(const short8v*)&Bb[(wn * 64 + jf * 16 + c) * 72 + kk * 32 + g * 8];
            #pragma unroll
            for (int nf = 0; nf < 8; ++nf)
                #pragma unroll
                for (int jf = 0; jf < 4; ++jf)
                    acc[nf][jf] = __builtin_amdgcn_mfma_f32_16x16x32_bf16(
                        a[nf], b[jf], acc[nf][jf], 0, 0, 0);
        }
        __builtin_amdgcn_s_setprio(0);
        __builtin_amdgcn_sched_barrier(0);
        __builtin_amdgcn_s_barrier();                        // reads done before reuse
    }

    // C layout: col(j) = lane&15, row(n) = (lane>>4)*4 + reg.
    #pragma unroll
    for (int nf = 0; nf < 8; ++nf) {
        #pragma unroll
        for (int rr = 0; rr < 4; ++rr) {
            float mx = acc[nf][0][rr];
            #pragma unroll
            for (int jf = 1; jf < 4; ++jf) mx = fmaxf(mx, acc[nf][jf][rr]);
            #pragma unroll
            for (int off = 1; off < 16; off <<= 1)
                mx = fmaxf(mx, __shfl_xor(mx, off, 64));
            if (c == 0)
                smin[wn >> 1][wm * 128 + nf * 16 + g * 4 + rr][wn & 1] = mx;
        }
    }
    __syncthreads();
    {
        const int th = tid >> 8, row = tid & 255;            // 2 x 256
        float v = fmaxf(smin[th][row][0], smin[th][row][1]);
        tilemin[(size_t)(bx * 2 + th) * N_VEC + n0 + row] = -2.0f * v;
    }
}

// ---------------------------------------------------------------------------
// Stage B1a: thr[n] = min_t tilemin[t][n] + MARGIN; also re-arms keys[n].
__global__ __launch_bounds__(256) void k_rowmin(const float* __restrict__ tilemin,
                                               float* __restrict__ thr,
                                               unsigned long long* __restrict__ keys) {
    __shared__ float red[4][64];
    const int nl = threadIdx.x & 63, tg = threadIdx.x >> 6;
    const int n = blockIdx.x * 64 + nl;
    float m = 3.4e38f;
    #pragma unroll
    for (int i = 0; i < 16; ++i)
        m = fminf(m, tilemin[(size_t)(tg * 16 + i) * N_VEC + n]);
    red[tg][nl] = m;
    __syncthreads();
    if (tg == 0) {
        thr[n] = fminf(fminf(red[0][nl], red[1][nl]),
                       fminf(red[2][nl], red[3][nl])) + MARGIN;
        keys[n] = ~0ull;
    }
}

// ---------------------------------------------------------------------------
// Stage B1b: build per-tile candidate lists (wave-aggregated compaction).
__global__ __launch_bounds__(256) void k_build(const float* __restrict__ tilemin,
                                               const float* __restrict__ thr,
                                               int* __restrict__ listlen,
                                               int* __restrict__ lists) {
    const int t = blockIdx.x;
    const int lane = threadIdx.x & 63;
    #pragma unroll
    for (int it = 0; it < 8; ++it) {
        int n = blockIdx.y * 2048 + it * 256 + threadIdx.x;
        bool qq = tilemin[(size_t)t * N_VEC + n] <= thr[n];
        unsigned long long mask = __ballot(qq);
        if (mask) {
            int ldr = __ffsll(mask) - 1;
            int base = 0;
            if (lane == ldr) base = atomicAdd(&listlen[t], __popcll(mask));
            base = __shfl(base, ldr, 64);
            if (qq) {
                int pre = __popcll(mask & ((1ull << lane) - 1ull));
                lists[t * N_VEC + base + pre] = n;
            }
        }
    }
}

// ---------------------------------------------------------------------------
// Stage B2: tile-centric exact refine.  grid (64, 128).  Reads z directly in
// its original (B,C,H,W) layout.
__global__ __launch_bounds__(256) void k_refine2(const float* __restrict__ z,
                                                 const float* __restrict__ cb,
                                                 const float* __restrict__ ce,
                                                 const float* __restrict__ A,
                                                 const int* __restrict__ listlen,
                                                 const int* __restrict__ lists,
                                                 unsigned long long* __restrict__ keys) {
    __shared__ float e_s[128 * 68];
    __shared__ float z_s[32 * 68];
    __shared__ int   rows_s[32];

    const int t = blockIdx.x;
    const int len = listlen[t];
    const int tid = threadIdx.x;
    const int jg = tid & 31, rg = tid >> 5;
    const int j0 = t * 128;

    for (int b0 = blockIdx.y * 32; b0 < len; b0 += 128 * 32) {
        const int nrows = min(32, len - b0);
        __syncthreads();                           // protect prev batch's LDS
        if (tid < 32)
            rows_s[tid] = lists[t * N_VEC + b0 + min(tid, nrows - 1)];  // pad dup row0

        float acc[4][4];
        #pragma unroll
        for (int rr = 0; rr < 4; ++rr)
            #pragma unroll
            for (int jj = 0; jj < 4; ++jj) acc[rr][jj] = 0.0f;

        for (int kc = 0; kc < C_DIM; kc += 64) {
            __syncthreads();
            {   // stage e chunk: 128 j x 64 k
                int jr = tid >> 1, ko = (tid & 1) * 32;
                #pragma unroll
                for (int i = 0; i < 8; ++i)
                    *(float4*)&e_s[jr * 68 + ko + i * 4] =
                        *(const float4*)&cb[(size_t)(j0 + jr) * C_DIM + kc + ko + i * 4];
            }
            {   // stage z chunk: 32 rows x 64 k from original layout
                int rr = tid & 31, ks = tid >> 5;
                int n = rows_s[rr];
                int bb = n >> 10, hw = n & 1023;
                const float* zp = z + (size_t)bb * 262144 + hw;
                #pragma unroll
                for (int i = 0; i < 8; ++i) {
                    int k = kc + ks * 8 + i;
                    z_s[rr * 68 + ks * 8 + i] = zp[(size_t)k * 1024];
                }
            }
            __syncthreads();

            #pragma unroll
            for (int k4 = 0; k4 < 16; ++k4) {
                float4 ef[4], zf[4];
                #pragma unroll
                for (int jj = 0; jj < 4; ++jj)
                    ef[jj] = *(const float4*)&e_s[(jg + 32 * jj) * 68 + k4 * 4];
                #pragma unroll
                for (int rr = 0; rr < 4; ++rr)
                    zf[rr] = *(const float4*)&z_s[(rg * 4 + rr) * 68 + k4 * 4];
                #pragma unroll
                for (int kk = 0; kk < 4; ++kk)       // k ascending: exact chain
                    #pragma unroll
                    for (int rr = 0; rr < 4; ++rr)
                        #pragma unroll
                        for (int jj = 0; jj < 4; ++jj)
                            acc[rr][jj] = fmaf(((const float*)&zf[rr])[kk],
                                               ((const float*)&ef[jj])[kk], acc[rr][jj]);
            }
        }

        // epilogue: exact d, packed key, min over jj then over jg lanes
        #pragma unroll
        for (int rr = 0; rr < 4; ++rr) {
            const int n = rows_s[rg * 4 + rr];
            const float An = A[n];
            unsigned long long best = ~0ull;
            #pragma unroll
            for (int jj = 0; jj < 4; ++jj) {
                int j = j0 + jg + 32 * jj;
                float tt = An + ce[j];
                float d = fmaf(-2.0f, acc[rr][jj], tt);   // == R2 epilogue bits
                unsigned int sd = __float_as_uint(d);
                sd = (sd & 0x80000000u) ? ~sd : (sd | 0x80000000u);
                unsigned long long key = ((unsigned long long)sd << 32) | (unsigned)j;
                best = key < best ? key : best;
            }
            #pragma unroll
            for (int off = 16; off > 0; off >>= 1) {      // reduce 32 jg lanes
                unsigned long long o = __shfl_xor(best, off, 64);
                best = o < best ? o : best;
            }
            if (jg == 0) atomicMin(&keys[n], best);
        }
    }
}

// ---------------------------------------------------------------------------
// gather z_q + idx unpack + histogram + fp64 SSE reduction
__global__ __launch_bounds__(256) void k_gather(const float* __restrict__ z,
                                                const float* __restrict__ cb,
                                                const unsigned long long* __restrict__ keys,
                                                float* __restrict__ out,
                                                float* __restrict__ out_idx,
                                                int* __restrict__ counts,
                                                double* __restrict__ sse) {
    int bh = blockIdx.x;                 // b*32 + h
    int b = bh >> 5, h = bh & 31;
    int tid = threadIdx.x;
    __shared__ int sidx[32];
    if (tid < 32) {
        int n = b * 1024 + h * 32 + tid;
        unsigned long long k = keys[n];
        int idx = (int)(k & 0xFFFFFFFFull);
        sidx[tid] = idx;
        out_idx[n] = (float)idx;
        atomicAdd(&counts[idx], 1);
    }
    __syncthreads();
    int w = tid & 31, cy = tid >> 5;
    int jid = sidx[w];
    const float* cbr = cb + (size_t)jid * C_DIM;
    size_t zb = (size_t)b * 262144 + h * 32 + w;

    double acc = 0.0;
    #pragma unroll 4
    for (int cc = 0; cc < 32; ++cc) {
        int c = cc * 8 + cy;
        float e = cbr[c];
        size_t zi = zb + (size_t)c * 1024;
        float d = e - z[zi];
        out[zi] = e;
        acc += (double)(d * d);
    }
    #pragma unroll
    for (int off = 32; off > 0; off >>= 1) acc += __shfl_down(acc, off, 64);
    __shared__ double sh[4];
    if ((tid & 63) == 0) sh[tid >> 6] = acc;
    __syncthreads();
    if (tid == 0) atomicAdd(sse, sh[0] + sh[1] + sh[2] + sh[3]);
}

// ---------------------------------------------------------------------------
// Gram matrix M = Wn^T Wn  (256x256), j-split with float atomics
__global__ __launch_bounds__(256) void k_gram(const float* __restrict__ cb,
                                              const float* __restrict__ rn,
                                              float* __restrict__ M) {
    __shared__ float aT[64][68];
    __shared__ float bT[64][68];
    int k0 = blockIdx.x * 64, l0 = blockIdx.y * 64;
    int jc0 = blockIdx.z * 256;
    int tid = threadIdx.x;
    int tk = tid & 15, tl = tid >> 4;
    float acc[4][4];
    #pragma unroll
    for (int i = 0; i < 4; ++i)
        #pragma unroll
        for (int l = 0; l < 4; ++l) acc[i][l] = 0.0f;

    for (int jc = jc0; jc < jc0 + 256; jc += 64) {
        __syncthreads();
        {
            int kk = tid & 63, jj0 = tid >> 6;
            #pragma unroll
            for (int p = 0; p < 16; ++p) {
                int jj = p * 4 + jj0;
                float r = rn[jc + jj];
                const float* row = cb + (size_t)(jc + jj) * C_DIM;
                aT[jj][kk] = row[k0 + kk] * r;
                bT[jj][kk] = row[l0 + kk] * r;
            }
        }
        __syncthreads();
        #pragma unroll 8
        for (int jj = 0; jj < 64; ++jj) {
            float4 av = *(const float4*)&aT[jj][tk * 4];
            float4 bv = *(const float4*)&bT[jj][tl * 4];
            float a4[4] = {av.x, av.y, av.z, av.w};
            float b4[4] = {bv.x, bv.y, bv.z, bv.w};
            #pragma unroll
            for (int i = 0; i < 4; ++i)
                #pragma unroll
                for (int l = 0; l < 4; ++l)
                    acc[i][l] = fmaf(a4[i], b4[l], acc[i][l]);
        }
    }
    #pragma unroll
    for (int i = 0; i < 4; ++i)
        #pragma unroll
        for (int l = 0; l < 4; ++l)
            atomicAdd(&M[(size_t)(k0 + tk * 4 + i) * C_DIM + l0 + tl * 4 + l], acc[i][l]);
}

// ---------------------------------------------------------------------------
// finalize scalars: loss, ortho = (||M||_F^2 - n_e)/n_e^2, perplexity
__global__ __launch_bounds__(256) void k_final(const float* __restrict__ M,
                                               const int* __restrict__ counts,
                                               const double* __restrict__ accum,
                                               float* __restrict__ out_scalars) {
    int tid = threadIdx.x;
    __shared__ double sh[4];

    double s = 0.0;
    for (int i = tid; i < C_DIM * C_DIM; i += 256) {
        double m = M[i];
        s += m * m;
    }
    #pragma unroll
    for (int off = 32; off > 0; off >>= 1) s += __shfl_down(s, off, 64);
    if ((tid & 63) == 0) sh[tid >> 6] = s;
    __syncthreads();
    double S = sh[0] + sh[1] + sh[2] + sh[3];
    __syncthreads();

    double H = 0.0;
    for (int j = tid; j < N_E; j += 256) {
        double p = counts[j] * (1.0 / (double)N_VEC);
        H += p * log(p + 1e-10);
    }
    #pragma unroll
    for (int off = 32; off > 0; off >>= 1) H += __shfl_down(H, off, 64);
    if ((tid & 63) == 0) sh[tid >> 6] = H;
    __syncthreads();

    if (tid == 0) {
        double Hs = sh[0] + sh[1] + sh[2] + sh[3];
        out_scalars[0] = (float)(1.25 * accum[0] / (double)N_ELEM);        // loss
        out_scalars[1] = (float)((S - (double)N_E) / ((double)N_E * N_E)); // ortho
        out_scalars[2] = (float)exp(-Hs);                                  // perplexity
    }
}

// ---------------------------------------------------------------------------
extern "C" void kernel_launch(void* const* d_in, const int* in_sizes, int n_in,
                              void* d_out, int out_size, void* d_ws, size_t ws_size,
                              hipStream_t stream) {
    (void)in_sizes; (void)n_in; (void)out_size; (void)ws_size;
    const float* z  = (const float*)d_in[0];
    const float* cb = (const float*)d_in[1];
    float* out = (float*)d_out;

    char* ws = (char*)d_ws;
    int* counts            = (int*)(ws + WS_COUNTS);
    float* M               = (float*)(ws + WS_M);
    double* accum          = (double*)(ws + WS_ACCUM);
    int* listlen           = (int*)(ws + WS_LISTLEN);
    float* ce              = (float*)(ws + WS_CE);
    float* rn              = (float*)(ws + WS_RN);
    float* A               = (float*)(ws + WS_A);
    unsigned long long* keys = (unsigned long long*)(ws + WS_KEYS);
    int* lists             = (int*)(ws + WS_LISTS);
    float* tilemin         = (float*)(ws + WS_TILEMIN);
    unsigned short* zbf    = (unsigned short*)(ws + WS_ZBF);
    unsigned short* cbbf   = (unsigned short*)(ws + WS_CBBF);
    float* thr             = (float*)(ws + WS_THR);

    float* out_scalars = out + N_ELEM;       // loss, ortho, perplexity
    float* out_idx     = out + N_ELEM + 3;   // 16384 idx as float

    // allow 144 KB dynamic LDS for k_mfma (host-side attr, graph-capture safe)
    hipFuncSetAttribute(reinterpret_cast<const void*>(&k_mfma),
                        hipFuncAttributeMaxDynamicSharedMemorySize,
                        2 * AMF_LDSB * (int)sizeof(unsigned short));

    hipMemsetAsync(ws, 0, WS_ZERO_BYTES, stream);   // counts + M + accum + listlen

    k_cbprep<<<N_E, 256, 0, stream>>>(cb, ce, rn, cbbf);
    k_ztrans<<<dim3(N_VEC / 256, 4), 256, 0, stream>>>(z, zbf, A);
    k_mfma<<<2048, 512, 2 * AMF_LDSB * sizeof(unsigned short), stream>>>(zbf, cbbf, tilemin);
    k_rowmin<<<N_VEC / 64, 256, 0, stream>>>(tilemin, thr, keys);
    k_build<<<dim3(64, 8), 256, 0, stream>>>(tilemin, thr, listlen, lists);
    k_refine2<<<dim3(64, 128), 256, 0, stream>>>(z, cb, ce, A, listlen, lists, keys);
    k_gather<<<512, 256, 0, stream>>>(z, cb, keys, out, out_idx, counts, accum);
    k_gram<<<dim3(4, 4, 32), 256, 0, stream>>>(cb, rn, M);
    k_final<<<1, 256, 0, stream>>>(M, counts, accum, out_scalars);
}

// Round 10
// 441.160 us; speedup vs baseline: 1.0460x; 1.0460x over previous
//
#include <hip/hip_runtime.h>
#include <hip/hip_bf16.h>
#include <math.h>

// ---------------------------------------------------------------------------
// VQ quantizer:
//   in[0] = z        (16,256,32,32) fp32   -> N=16384 vectors of C=256
//   in[1] = codebook (8192,256)     fp32
//   out   = [ z_q (B,C,H,W) 4194304 | loss | ortho | perplexity | idx(16384) as float ]
//
// idx strategy (two-stage, bit-matching the R2..R7 passing semantics):
//   Stage A: bf16 MFMA GEMM; tilemin[t][n] = -2*max_j dot_approx (err<=1.54e-4)
//   Stage B: rows whose tilemin is within MARGIN of rowmin get the EXACT fp32
//            chain recomputed tile-centrically; d = fmaf(-2,acc, A_n + ce_j)
//            == R2 bits; packed-key atomicMin, lowest-index tie-break.
//
// R10 = R7 green build, with only the znorm/ztrans split kept from R9
// (value-verified by R9's passing first call). refine2/mfma are R7-verbatim.
// ---------------------------------------------------------------------------

#define N_E     8192
#define C_DIM   256
#define N_VEC   16384            // 16*32*32
#define N_ELEM  4194304          // 16*256*32*32
#define MARGIN  6.0e-4f

// ws layout (bytes) -- zero-init fields packed first (single memset)
#define WS_COUNTS   0            // int[8192]                 32768
#define WS_M        32768        // float[65536]              262144
#define WS_ACCUM    294912       // double[2]                 16
#define WS_LISTLEN  294928       // int[64]                   256
#define WS_ZERO_BYTES 295184
#define WS_CE       295184       // float[8192]               32768
#define WS_RN       327952       // float[8192]               32768
#define WS_A        360720       // float[16384]              65536
#define WS_KEYS     426256       // u64[16384]                131072
#define WS_LISTS    557328       // int[64*16384]             4194304
#define WS_TILEMIN  4751632      // float[64*16384] [t][n]    4194304
#define WS_ZBF      8945936      // ushort[16384*256]         8388608
#define WS_CBBF     17334544     // ushort[8192*256]          4194304
#define WS_THR      21528848     // float[16384]              65536

typedef short short8v __attribute__((ext_vector_type(8)));
typedef float f32x4  __attribute__((ext_vector_type(4)));

__device__ inline unsigned short f2bf(float f) {       // RNE fp32->bf16 (no NaN in data)
    unsigned int x = __float_as_uint(f);
    return (unsigned short)((x + 0x7fffu + ((x >> 16) & 1u)) >> 16);
}

// ---------------------------------------------------------------------------
// codebook prep: row sqnorm ce (bits == R2..R7), recip norm rn, bf16 cast
__global__ __launch_bounds__(256) void k_cbprep(const float* __restrict__ cb,
                                                float* __restrict__ ce,
                                                float* __restrict__ rn,
                                                unsigned short* __restrict__ cbbf) {
    int j = blockIdx.x;
    int tid = threadIdx.x;
    float v = cb[(size_t)j * C_DIM + tid];
    cbbf[(size_t)j * C_DIM + tid] = f2bf(v);
    float s = v * v;
    #pragma unroll
    for (int off = 32; off > 0; off >>= 1) s += __shfl_down(s, off, 64);
    __shared__ float sh[4];
    if ((tid & 63) == 0) sh[tid >> 6] = s;
    __syncthreads();
    if (tid == 0) {
        float t = sh[0] + sh[1] + sh[2] + sh[3];
        ce[j] = t;
        rn[j] = 1.0f / sqrtf(t);
    }
}

// ---------------------------------------------------------------------------
// z row squared norms (R2-verbatim chain -> A bits identical)
__global__ __launch_bounds__(256) void k_znorm(const float* __restrict__ z,
                                               float* __restrict__ A) {
    int n = blockIdx.x * 256 + threadIdx.x;      // n = b*1024 + hw
    int b = n >> 10, hw = n & 1023;
    const float* zp = z + (size_t)b * 262144 + hw;
    float a = 0.0f;
    #pragma unroll 8
    for (int c = 0; c < C_DIM; ++c) {
        float v = zp[(size_t)c * 1024];
        a = fmaf(v, v, a);
    }
    A[n] = a;
}

// ---------------------------------------------------------------------------
// z -> zbf transpose with COALESCED writes: stage 64n x 256c fp32 in LDS,
// then each thread writes a contiguous 128B run of a zbf row (16B/lane).
// (value-verified: R9's first-call validation passed with this kernel)
__global__ __launch_bounds__(256) void k_ztrans(const float* __restrict__ z,
                                                unsigned short* __restrict__ zbf) {
    __shared__ float tile[64 * 260];             // [hw][c], stride 260
    const int tid = threadIdx.x;
    const int n0 = blockIdx.x * 64;
    const int b = n0 >> 10, hw0 = n0 & 1023;
    const float* zp = z + (size_t)b * 262144 + hw0;

    const int hw = tid & 63, cg = tid >> 6;      // 4 c per pass, coalesced over hw
    #pragma unroll 8
    for (int p = 0; p < 64; ++p) {
        int c = p * 4 + cg;
        tile[hw * 260 + c] = zp[(size_t)c * 1024 + hw];
    }
    __syncthreads();

    const int r = tid >> 2, q = tid & 3;         // row, 64-c quarter
    unsigned short* dst = zbf + (size_t)(n0 + r) * C_DIM + q * 64;
    const float* src = &tile[r * 260 + q * 64];
    #pragma unroll
    for (int i = 0; i < 8; ++i) {
        f32x4 lo = *(const f32x4*)&src[i * 8];
        f32x4 hi = *(const f32x4*)&src[i * 8 + 4];
        short8v u;
        #pragma unroll
        for (int x = 0; x < 4; ++x) { u[x] = (short)f2bf(lo[x]); u[4 + x] = (short)f2bf(hi[x]); }
        *(short8v*)(dst + i * 8) = u;            // 16B/lane, rows contiguous
    }
}

// ---------------------------------------------------------------------------
// Stage A (R7-verbatim): bf16 MFMA GEMM, 128n x 128j per block (4 waves, 2x2),
// K=256, 2-level XCD swizzle, reg-staged prefetch.
__global__ __launch_bounds__(256) void k_mfma(const unsigned short* __restrict__ zbf,
                                              const unsigned short* __restrict__ cbbf,
                                              float* __restrict__ tilemin) {
    __shared__ unsigned short As[128 * 72];   // [n][k]
    __shared__ unsigned short Bs[128 * 72];   // [j][k]
    __shared__ float smin[128][2];

    const int tid = threadIdx.x;
    const int lin = blockIdx.x;
    const int x = lin & 7, r = lin >> 3;                  // XCD, rank within
    const int jp = r >> 7, q = r & 127;
    const int by = x * 16 + (q >> 3), bx = jp * 8 + (q & 7);
    const int n0 = by * 128, j0 = bx * 128;
    const int wave = tid >> 6, lane = tid & 63;
    const int wx = wave & 1, wy = wave >> 1;              // wave tile: 64n x 64j
    const int g = lane >> 4, c = lane & 15;
    const int kg = tid & 7, nl = tid >> 3;                // staging decomposition

    short8v ra[4], rb[4];
    #pragma unroll
    for (int p = 0; p < 4; ++p) {
        int row = nl + 32 * p;
        ra[p] = *(const short8v*)&zbf[(size_t)(n0 + row) * C_DIM + kg * 8];
        rb[p] = *(const short8v*)&cbbf[(size_t)(j0 + row) * C_DIM + kg * 8];
    }

    f32x4 acc[4][4];
    #pragma unroll
    for (int i = 0; i < 4; ++i)
        #pragma unroll
        for (int j = 0; j < 4; ++j) acc[i][j] = (f32x4){0.f, 0.f, 0.f, 0.f};

    for (int kc = 0; kc < C_DIM; kc += 64) {
        __syncthreads();                                  // prev consumers done
        #pragma unroll
        for (int p = 0; p < 4; ++p) {
            int row = nl + 32 * p;
            *(short8v*)&As[row * 72 + kg * 8] = ra[p];
            *(short8v*)&Bs[row * 72 + kg * 8] = rb[p];
        }
        __syncthreads();
        if (kc < C_DIM - 64) {                            // prefetch next chunk
            #pragma unroll
            for (int p = 0; p < 4; ++p) {
                int row = nl + 32 * p;
                ra[p] = *(const short8v*)&zbf[(size_t)(n0 + row) * C_DIM + kc + 64 + kg * 8];
                rb[p] = *(const short8v*)&cbbf[(size_t)(j0 + row) * C_DIM + kc + 64 + kg * 8];
            }
        }

        #pragma unroll
        for (int kk = 0; kk < 64; kk += 32) {
            short8v a[4], b[4];
            #pragma unroll
            for (int f = 0; f < 4; ++f)
                a[f] = *(const short8v*)&As[(wy * 64 + f * 16 + c) * 72 + kk + g * 8];
            #pragma unroll
            for (int f = 0; f < 4; ++f)
                b[f] = *(const short8v*)&Bs[(wx * 64 + f * 16 + c) * 72 + kk + g * 8];
            #pragma unroll
            for (int nf = 0; nf < 4; ++nf)
                #pragma unroll
                for (int jf = 0; jf < 4; ++jf)
                    acc[nf][jf] = __builtin_amdgcn_mfma_f32_16x16x32_bf16(
                        a[nf], b[jf], acc[nf][jf], 0, 0, 0);
        }
    }

    // C layout: col(j) = lane&15, row(n) = (lane>>4)*4 + reg.  max over j.
    #pragma unroll
    for (int nf = 0; nf < 4; ++nf) {
        #pragma unroll
        for (int rr = 0; rr < 4; ++rr) {
            float mx = acc[nf][0][rr];
            #pragma unroll
            for (int jf = 1; jf < 4; ++jf) mx = fmaxf(mx, acc[nf][jf][rr]);
            #pragma unroll
            for (int off = 1; off < 16; off <<= 1)
                mx = fmaxf(mx, __shfl_xor(mx, off, 64));
            if (c == 0) smin[wy * 64 + nf * 16 + g * 4 + rr][wx] = -2.0f * mx;
        }
    }
    __syncthreads();
    if (tid < 128)
        tilemin[(size_t)bx * N_VEC + n0 + tid] = fminf(smin[tid][0], smin[tid][1]);
}

// ---------------------------------------------------------------------------
// Stage B1a: thr[n] = min_t tilemin[t][n] + MARGIN; also re-arms keys[n].
__global__ __launch_bounds__(256) void k_rowmin(const float* __restrict__ tilemin,
                                               float* __restrict__ thr,
                                               unsigned long long* __restrict__ keys) {
    __shared__ float red[4][64];
    const int nl = threadIdx.x & 63, tg = threadIdx.x >> 6;
    const int n = blockIdx.x * 64 + nl;
    float m = 3.4e38f;
    #pragma unroll
    for (int i = 0; i < 16; ++i)
        m = fminf(m, tilemin[(size_t)(tg * 16 + i) * N_VEC + n]);
    red[tg][nl] = m;
    __syncthreads();
    if (tg == 0) {
        thr[n] = fminf(fminf(red[0][nl], red[1][nl]),
                       fminf(red[2][nl], red[3][nl])) + MARGIN;
        keys[n] = ~0ull;
    }
}

// ---------------------------------------------------------------------------
// Stage B1b: build per-tile candidate lists (wave-aggregated compaction).
__global__ __launch_bounds__(256) void k_build(const float* __restrict__ tilemin,
                                               const float* __restrict__ thr,
                                               int* __restrict__ listlen,
                                               int* __restrict__ lists) {
    const int t = blockIdx.x;
    const int lane = threadIdx.x & 63;
    #pragma unroll
    for (int it = 0; it < 8; ++it) {
        int n = blockIdx.y * 2048 + it * 256 + threadIdx.x;
        bool qq = tilemin[(size_t)t * N_VEC + n] <= thr[n];
        unsigned long long mask = __ballot(qq);
        if (mask) {
            int ldr = __ffsll(mask) - 1;
            int base = 0;
            if (lane == ldr) base = atomicAdd(&listlen[t], __popcll(mask));
            base = __shfl(base, ldr, 64);
            if (qq) {
                int pre = __popcll(mask & ((1ull << lane) - 1ull));
                lists[t * N_VEC + base + pre] = n;
            }
        }
    }
}

// ---------------------------------------------------------------------------
// Stage B2 (R7-verbatim): tile-centric exact refine.  grid (64, 128).
// Reads z directly in its original (B,C,H,W) layout.
__global__ __launch_bounds__(256) void k_refine2(const float* __restrict__ z,
                                                 const float* __restrict__ cb,
                                                 const float* __restrict__ ce,
                                                 const float* __restrict__ A,
                                                 const int* __restrict__ listlen,
                                                 const int* __restrict__ lists,
                                                 unsigned long long* __restrict__ keys) {
    __shared__ float e_s[128 * 68];
    __shared__ float z_s[32 * 68];
    __shared__ int   rows_s[32];

    const int t = blockIdx.x;
    const int len = listlen[t];
    const int tid = threadIdx.x;
    const int jg = tid & 31, rg = tid >> 5;
    const int j0 = t * 128;

    for (int b0 = blockIdx.y * 32; b0 < len; b0 += 128 * 32) {
        const int nrows = min(32, len - b0);
        __syncthreads();                           // protect prev batch's LDS
        if (tid < 32)
            rows_s[tid] = lists[t * N_VEC + b0 + min(tid, nrows - 1)];  // pad dup row0

        float acc[4][4];
        #pragma unroll
        for (int rr = 0; rr < 4; ++rr)
            #pragma unroll
            for (int jj = 0; jj < 4; ++jj) acc[rr][jj] = 0.0f;

        for (int kc = 0; kc < C_DIM; kc += 64) {
            __syncthreads();
            {   // stage e chunk: 128 j x 64 k
                int jr = tid >> 1, ko = (tid & 1) * 32;
                #pragma unroll
                for (int i = 0; i < 8; ++i)
                    *(float4*)&e_s[jr * 68 + ko + i * 4] =
                        *(const float4*)&cb[(size_t)(j0 + jr) * C_DIM + kc + ko + i * 4];
            }
            {   // stage z chunk: 32 rows x 64 k from original layout
                int rr = tid & 31, ks = tid >> 5;
                int n = rows_s[rr];
                int bb = n >> 10, hw = n & 1023;
                const float* zp = z + (size_t)bb * 262144 + hw;
                #pragma unroll
                for (int i = 0; i < 8; ++i) {
                    int k = kc + ks * 8 + i;
                    z_s[rr * 68 + ks * 8 + i] = zp[(size_t)k * 1024];
                }
            }
            __syncthreads();

            #pragma unroll
            for (int k4 = 0; k4 < 16; ++k4) {
                float4 ef[4], zf[4];
                #pragma unroll
                for (int jj = 0; jj < 4; ++jj)
                    ef[jj] = *(const float4*)&e_s[(jg + 32 * jj) * 68 + k4 * 4];
                #pragma unroll
                for (int rr = 0; rr < 4; ++rr)
                    zf[rr] = *(const float4*)&z_s[(rg * 4 + rr) * 68 + k4 * 4];
                #pragma unroll
                for (int kk = 0; kk < 4; ++kk)       // k ascending: exact chain
                    #pragma unroll
                    for (int rr = 0; rr < 4; ++rr)
                        #pragma unroll
                        for (int jj = 0; jj < 4; ++jj)
                            acc[rr][jj] = fmaf(((const float*)&zf[rr])[kk],
                                               ((const float*)&ef[jj])[kk], acc[rr][jj]);
            }
        }

        // epilogue: exact d, packed key, min over jj then over jg lanes
        #pragma unroll
        for (int rr = 0; rr < 4; ++rr) {
            const int n = rows_s[rg * 4 + rr];
            const float An = A[n];
            unsigned long long best = ~0ull;
            #pragma unroll
            for (int jj = 0; jj < 4; ++jj) {
                int j = j0 + jg + 32 * jj;
                float tt = An + ce[j];
                float d = fmaf(-2.0f, acc[rr][jj], tt);   // == R2 epilogue bits
                unsigned int sd = __float_as_uint(d);
                sd = (sd & 0x80000000u) ? ~sd : (sd | 0x80000000u);
                unsigned long long key = ((unsigned long long)sd << 32) | (unsigned)j;
                best = key < best ? key : best;
            }
            #pragma unroll
            for (int off = 16; off > 0; off >>= 1) {      // reduce 32 jg lanes
                unsigned long long o = __shfl_xor(best, off, 64);
                best = o < best ? o : best;
            }
            if (jg == 0) atomicMin(&keys[n], best);
        }
    }
}

// ---------------------------------------------------------------------------
// gather z_q + idx unpack + histogram + fp64 SSE reduction
__global__ __launch_bounds__(256) void k_gather(const float* __restrict__ z,
                                                const float* __restrict__ cb,
                                                const unsigned long long* __restrict__ keys,
                                                float* __restrict__ out,
                                                float* __restrict__ out_idx,
                                                int* __restrict__ counts,
                                                double* __restrict__ sse) {
    int bh = blockIdx.x;                 // b*32 + h
    int b = bh >> 5, h = bh & 31;
    int tid = threadIdx.x;
    __shared__ int sidx[32];
    if (tid < 32) {
        int n = b * 1024 + h * 32 + tid;
        unsigned long long k = keys[n];
        int idx = (int)(k & 0xFFFFFFFFull);
        sidx[tid] = idx;
        out_idx[n] = (float)idx;
        atomicAdd(&counts[idx], 1);
    }
    __syncthreads();
    int w = tid & 31, cy = tid >> 5;
    int jid = sidx[w];
    const float* cbr = cb + (size_t)jid * C_DIM;
    size_t zb = (size_t)b * 262144 + h * 32 + w;

    double acc = 0.0;
    #pragma unroll 4
    for (int cc = 0; cc < 32; ++cc) {
        int c = cc * 8 + cy;
        float e = cbr[c];
        size_t zi = zb + (size_t)c * 1024;
        float d = e - z[zi];
        out[zi] = e;
        acc += (double)(d * d);
    }
    #pragma unroll
    for (int off = 32; off > 0; off >>= 1) acc += __shfl_down(acc, off, 64);
    __shared__ double sh[4];
    if ((tid & 63) == 0) sh[tid >> 6] = acc;
    __syncthreads();
    if (tid == 0) atomicAdd(sse, sh[0] + sh[1] + sh[2] + sh[3]);
}

// ---------------------------------------------------------------------------
// Gram matrix M = Wn^T Wn  (256x256), j-split with float atomics
__global__ __launch_bounds__(256) void k_gram(const float* __restrict__ cb,
                                              const float* __restrict__ rn,
                                              float* __restrict__ M) {
    __shared__ float aT[64][68];
    __shared__ float bT[64][68];
    int k0 = blockIdx.x * 64, l0 = blockIdx.y * 64;
    int jc0 = blockIdx.z * 256;
    int tid = threadIdx.x;
    int tk = tid & 15, tl = tid >> 4;
    float acc[4][4];
    #pragma unroll
    for (int i = 0; i < 4; ++i)
        #pragma unroll
        for (int l = 0; l < 4; ++l) acc[i][l] = 0.0f;

    for (int jc = jc0; jc < jc0 + 256; jc += 64) {
        __syncthreads();
        {
            int kk = tid & 63, jj0 = tid >> 6;
            #pragma unroll
            for (int p = 0; p < 16; ++p) {
                int jj = p * 4 + jj0;
                float r = rn[jc + jj];
                const float* row = cb + (size_t)(jc + jj) * C_DIM;
                aT[jj][kk] = row[k0 + kk] * r;
                bT[jj][kk] = row[l0 + kk] * r;
            }
        }
        __syncthreads();
        #pragma unroll 8
        for (int jj = 0; jj < 64; ++jj) {
            float4 av = *(const float4*)&aT[jj][tk * 4];
            float4 bv = *(const float4*)&bT[jj][tl * 4];
            float a4[4] = {av.x, av.y, av.z, av.w};
            float b4[4] = {bv.x, bv.y, bv.z, bv.w};
            #pragma unroll
            for (int i = 0; i < 4; ++i)
                #pragma unroll
                for (int l = 0; l < 4; ++l)
                    acc[i][l] = fmaf(a4[i], b4[l], acc[i][l]);
        }
    }
    #pragma unroll
    for (int i = 0; i < 4; ++i)
        #pragma unroll
        for (int l = 0; l < 4; ++l)
            atomicAdd(&M[(size_t)(k0 + tk * 4 + i) * C_DIM + l0 + tl * 4 + l], acc[i][l]);
}

// ---------------------------------------------------------------------------
// finalize scalars: loss, ortho = (||M||_F^2 - n_e)/n_e^2, perplexity
__global__ __launch_bounds__(256) void k_final(const float* __restrict__ M,
                                               const int* __restrict__ counts,
                                               const double* __restrict__ accum,
                                               float* __restrict__ out_scalars) {
    int tid = threadIdx.x;
    __shared__ double sh[4];

    double s = 0.0;
    for (int i = tid; i < C_DIM * C_DIM; i += 256) {
        double m = M[i];
        s += m * m;
    }
    #pragma unroll
    for (int off = 32; off > 0; off >>= 1) s += __shfl_down(s, off, 64);
    if ((tid & 63) == 0) sh[tid >> 6] = s;
    __syncthreads();
    double S = sh[0] + sh[1] + sh[2] + sh[3];
    __syncthreads();

    double H = 0.0;
    for (int j = tid; j < N_E; j += 256) {
        double p = counts[j] * (1.0 / (double)N_VEC);
        H += p * log(p + 1e-10);
    }
    #pragma unroll
    for (int off = 32; off > 0; off >>= 1) H += __shfl_down(H, off, 64);
    if ((tid & 63) == 0) sh[tid >> 6] = H;
    __syncthreads();

    if (tid == 0) {
        double Hs = sh[0] + sh[1] + sh[2] + sh[3];
        out_scalars[0] = (float)(1.25 * accum[0] / (double)N_ELEM);        // loss
        out_scalars[1] = (float)((S - (double)N_E) / ((double)N_E * N_E)); // ortho
        out_scalars[2] = (float)exp(-Hs);                                  // perplexity
    }
}

// ---------------------------------------------------------------------------
extern "C" void kernel_launch(void* const* d_in, const int* in_sizes, int n_in,
                              void* d_out, int out_size, void* d_ws, size_t ws_size,
                              hipStream_t stream) {
    (void)in_sizes; (void)n_in; (void)out_size; (void)ws_size;
    const float* z  = (const float*)d_in[0];
    const float* cb = (const float*)d_in[1];
    float* out = (float*)d_out;

    char* ws = (char*)d_ws;
    int* counts            = (int*)(ws + WS_COUNTS);
    float* M               = (float*)(ws + WS_M);
    double* accum          = (double*)(ws + WS_ACCUM);
    int* listlen           = (int*)(ws + WS_LISTLEN);
    float* ce              = (float*)(ws + WS_CE);
    float* rn              = (float*)(ws + WS_RN);
    float* A               = (float*)(ws + WS_A);
    unsigned long long* keys = (unsigned long long*)(ws + WS_KEYS);
    int* lists             = (int*)(ws + WS_LISTS);
    float* tilemin         = (float*)(ws + WS_TILEMIN);
    unsigned short* zbf    = (unsigned short*)(ws + WS_ZBF);
    unsigned short* cbbf   = (unsigned short*)(ws + WS_CBBF);
    float* thr             = (float*)(ws + WS_THR);

    float* out_scalars = out + N_ELEM;       // loss, ortho, perplexity
    float* out_idx     = out + N_ELEM + 3;   // 16384 idx as float

    hipMemsetAsync(ws, 0, WS_ZERO_BYTES, stream);   // counts + M + accum + listlen

    k_cbprep<<<N_E, 256, 0, stream>>>(cb, ce, rn, cbbf);
    k_znorm<<<N_VEC / 256, 256, 0, stream>>>(z, A);
    k_ztrans<<<N_VEC / 64, 256, 0, stream>>>(z, zbf);
    k_mfma<<<8192, 256, 0, stream>>>(zbf, cbbf, tilemin);
    k_rowmin<<<N_VEC / 64, 256, 0, stream>>>(tilemin, thr, keys);
    k_build<<<dim3(64, 8), 256, 0, stream>>>(tilemin, thr, listlen, lists);
    k_refine2<<<dim3(64, 128), 256, 0, stream>>>(z, cb, ce, A, listlen, lists, keys);
    k_gather<<<512, 256, 0, stream>>>(z, cb, keys, out, out_idx, counts, accum);
    k_gram<<<dim3(4, 4, 32), 256, 0, stream>>>(cb, rn, M);
    k_final<<<1, 256, 0, stream>>>(M, counts, accum, out_scalars);
}